// Round 1
// baseline (416.900 us; speedup 1.0000x reference)
//
#include <hip/hip_runtime.h>
#include <hip/hip_bf16.h>

// SegmentConv2d: fake-quant-int8 (global for x, per-128-oc-chunk for w) + 3x3 pad1 conv + bias.
// Strategy: quantize to real int8, do the conv with mfma_i32_16x16x64_i8 (exact integer
// accumulation), scale+bias in epilogue.
//
// Shapes: x[8][256][128][128] f32, w[512][256][3][3] f32, bias[512], out[8][512][128][128] f32.
//
// ws layout:
//   [0..255]        : amax[5] (uint bits, atomicMax) + 16B zero area at +64 (OOB redirect)
//   [256 ..)        : qx int8 NHWC  [n][h][w][c]  = 33,554,432 B
//   [256+32M ..)    : qw int8       [r*3+s][oc][c] = 1,179,648 B

typedef int i32x4 __attribute__((ext_vector_type(4)));

__device__ __forceinline__ void llds16(const void* g, void* l) {
    __builtin_amdgcn_global_load_lds(
        (const __attribute__((address_space(1))) void*)g,
        (__attribute__((address_space(3))) void*)l,
        16, 0, 0);
}

// ---------------- amax kernels ----------------
__global__ void k_amax_x(const float4* __restrict__ x, unsigned* __restrict__ dst) {
    int tid = blockIdx.x * 256 + threadIdx.x;        // 524288 threads
    float m = 0.f;
#pragma unroll 4
    for (int k = 0; k < 16; ++k) {                    // 8,388,608 float4 total
        float4 v = x[(size_t)tid + (size_t)k * 524288];
        m = fmaxf(m, fmaxf(fmaxf(fabsf(v.x), fabsf(v.y)), fmaxf(fabsf(v.z), fabsf(v.w))));
    }
    for (int off = 32; off > 0; off >>= 1) m = fmaxf(m, __shfl_xor(m, off, 64));
    if ((threadIdx.x & 63) == 0) atomicMax(dst, __float_as_uint(m));
}

__global__ void k_amax_w(const float4* __restrict__ w4, unsigned* __restrict__ dst) {
    int tid = blockIdx.x * 256 + threadIdx.x;        // 0..73727 (288 blocks)
    int chunk = blockIdx.y;                           // 0..3
    float4 v = w4[(size_t)chunk * 73728 + tid];
    float m = fmaxf(fmaxf(fabsf(v.x), fabsf(v.y)), fmaxf(fabsf(v.z), fabsf(v.w)));
    for (int off = 32; off > 0; off >>= 1) m = fmaxf(m, __shfl_xor(m, off, 64));
    if ((threadIdx.x & 63) == 0) atomicMax(dst + 1 + chunk, __float_as_uint(m));
}

// ---------------- quantize x : NCHW f32 -> NHWC int8 ----------------
// block = one (n,h) row, 256 threads. LDS transpose, padded uint[128][17] (conflict-free).
__global__ void k_quant_x(const float* __restrict__ x, signed char* __restrict__ qx,
                          const unsigned* __restrict__ amaxb) {
    __shared__ unsigned tile[128 * 17];
    float scale = fmaxf(__uint_as_float(amaxb[0]), 1e-12f) / 127.0f;
    int row = blockIdx.x;                 // n*128 + h
    int n = row >> 7, h = row & 127;
    int t = threadIdx.x;
    int w = t & 127, chalf = t >> 7;      // within wave, w = w0 + lane (coalesced)
    for (int cc = 0; cc < 4; ++cc) {
#pragma unroll
        for (int i = 0; i < 8; ++i) {
            int c0 = cc * 64 + chalf * 32 + i * 4;
            unsigned packed = 0;
#pragma unroll
            for (int j = 0; j < 4; ++j) {
                float v = x[((size_t)(n * 256 + c0 + j) * 128 + h) * 128 + w];
                float qf = fminf(fmaxf(rintf(v / scale), -128.f), 127.f);
                int qi = (int)qf;
                packed |= ((unsigned)(qi & 255)) << (8 * j);
            }
            tile[w * 17 + chalf * 8 + i] = packed;
        }
        __syncthreads();
#pragma unroll
        for (int i = 0; i < 2; ++i) {
            int idx = t + i * 256;         // 0..511
            int w2 = idx >> 2, q4 = idx & 3;
            unsigned u0 = tile[w2 * 17 + q4 * 4 + 0];
            unsigned u1 = tile[w2 * 17 + q4 * 4 + 1];
            unsigned u2 = tile[w2 * 17 + q4 * 4 + 2];
            unsigned u3 = tile[w2 * 17 + q4 * 4 + 3];
            uint4 val = make_uint4(u0, u1, u2, u3);
            *(uint4*)&qx[((size_t)row * 128 + w2) * 256 + cc * 64 + q4 * 16] = val;
        }
        __syncthreads();
    }
}

// ---------------- quantize w : OIHW f32 -> [rs][oc][c] int8 ----------------
__global__ void k_quant_w(const float* __restrict__ wsrc, signed char* __restrict__ qw,
                          const unsigned* __restrict__ amaxb) {
    int idx = blockIdx.x * 256 + threadIdx.x;   // 131072 = 512 blocks
    int oc = idx >> 8, c = idx & 255;
    float scale = fmaxf(__uint_as_float(amaxb[1 + (oc >> 7)]), 1e-12f) / 127.0f;
    const float* src = wsrc + (size_t)idx * 9;
#pragma unroll
    for (int rs = 0; rs < 9; ++rs) {
        float qf = fminf(fmaxf(rintf(src[rs] / scale), -128.f), 127.f);
        qw[((size_t)(rs * 512 + oc)) * 256 + c] = (signed char)(int)qf;
    }
}

// ---------------- conv : implicit GEMM with mfma_i32_16x16x64_i8 ----------------
// grid (1024 rows, 8 oc-groups), block 256 (4 waves). Block tile: 64 oc x 128 px (one row).
// K-loop: r(3) x cb(4 blocks of 64 c); per step stage xs[130][64] + wt[3][64][64], then
// s(3) x 8 MFMA per wave (wave owns 64oc x 32px).
__global__ __launch_bounds__(256) void k_conv(
    const signed char* __restrict__ qx, const signed char* __restrict__ qw,
    const signed char* __restrict__ zb, const unsigned* __restrict__ amaxb,
    const float* __restrict__ bias, float* __restrict__ out) {
    __shared__ __align__(16) signed char xs[130 * 64];   // [w+1][c]  8320 B
    __shared__ __align__(16) signed char wt[3 * 64 * 64];// [s][oc][c] 12288 B
    int row = blockIdx.x, ocg = blockIdx.y;
    int n = row >> 7, h = row & 127;
    int t = threadIdx.x, wid = t >> 6, lane = t & 63;
    int p = lane & 15, hi = lane >> 4;

    i32x4 acc[4][2] = {};

    for (int r = 0; r < 3; ++r) {
        int hh = h - 1 + r;
        bool hok = (hh >= 0) && (hh < 128);
        const signed char* xrowbase = qx + (size_t)(n * 128 + (hok ? hh : 0)) * 32768;
        for (int cb = 0; cb < 4; ++cb) {
            // stage xs: 520 x 16B lane-loads, lane-linear LDS dest
#pragma unroll
            for (int i = 0; i < 3; ++i) {
                int idx = t + i * 256;
                if (idx < 520) {
                    int wr = idx >> 2, q4 = idx & 3;
                    int wg = wr - 1;
                    const signed char* src = (hok && wg >= 0 && wg < 128)
                        ? xrowbase + (size_t)wg * 256 + cb * 64 + q4 * 16
                        : zb;
                    llds16(src, xs + (i * 256 + wid * 64) * 16);
                }
            }
            // stage wt: 768 x 16B
#pragma unroll
            for (int i = 0; i < 3; ++i) {
                int idx = t + i * 256;
                int s = idx >> 8, rem = idx & 255;
                int oc = rem >> 2, q4 = rem & 3;
                const signed char* src = qw
                    + ((size_t)((r * 3 + s) * 512 + ocg * 64 + oc)) * 256 + cb * 64 + q4 * 16;
                llds16(src, wt + (i * 256 + wid * 64) * 16);
            }
            __syncthreads();
#pragma unroll
            for (int s = 0; s < 3; ++s) {
                i32x4 a[4], b[2];
#pragma unroll
                for (int mf = 0; mf < 4; ++mf)
                    a[mf] = *(const i32x4*)&wt[s * 4096 + (mf * 16 + p) * 64 + hi * 16];
#pragma unroll
                for (int nf = 0; nf < 2; ++nf)
                    b[nf] = *(const i32x4*)&xs[(wid * 32 + nf * 16 + p + s) * 64 + hi * 16];
#pragma unroll
                for (int mf = 0; mf < 4; ++mf)
#pragma unroll
                    for (int nf = 0; nf < 2; ++nf)
                        acc[mf][nf] = __builtin_amdgcn_mfma_i32_16x16x64_i8(
                            a[mf], b[nf], acc[mf][nf], 0, 0, 0);
            }
            __syncthreads();
        }
    }

    float sx = fmaxf(__uint_as_float(amaxb[0]), 1e-12f) / 127.0f;
    float sw = fmaxf(__uint_as_float(amaxb[1 + (ocg >> 1)]), 1e-12f) / 127.0f;
    float sc = sx * sw;
#pragma unroll
    for (int mf = 0; mf < 4; ++mf)
#pragma unroll
        for (int nf = 0; nf < 2; ++nf)
#pragma unroll
            for (int j = 0; j < 4; ++j) {
                int oc = ocg * 64 + mf * 16 + hi * 4 + j;
                int px = wid * 32 + nf * 16 + p;
                out[((size_t)(n * 512 + oc) * 128 + h) * 128 + px] =
                    (float)acc[mf][nf][j] * sc + bias[oc];
            }
}

extern "C" void kernel_launch(void* const* d_in, const int* in_sizes, int n_in,
                              void* d_out, int out_size, void* d_ws, size_t ws_size,
                              hipStream_t stream) {
    const float* x    = (const float*)d_in[0];
    const float* wgt  = (const float*)d_in[1];
    const float* bias = (const float*)d_in[2];
    float* out = (float*)d_out;

    unsigned* amaxb = (unsigned*)d_ws;
    signed char* qx = (signed char*)d_ws + 256;
    signed char* qw = (signed char*)d_ws + 256 + 33554432;
    const signed char* zb = (const signed char*)d_ws + 64;   // 16B zeros for OOB redirect

    hipMemsetAsync(d_ws, 0, 256, stream);   // amax slots + zero area (graph-capturable)

    k_amax_x<<<2048, 256, 0, stream>>>((const float4*)x, amaxb);
    k_amax_w<<<dim3(288, 4), 256, 0, stream>>>((const float4*)wgt, amaxb);
    k_quant_x<<<1024, 256, 0, stream>>>(x, qx, amaxb);
    k_quant_w<<<512, 256, 0, stream>>>(wgt, qw, amaxb);
    k_conv<<<dim3(1024, 8), 256, 0, stream>>>(qx, qw, zb, amaxb, bias, out);
}

// Round 2
// 365.399 us; speedup vs baseline: 1.1409x; 1.1409x over previous
//
#include <hip/hip_runtime.h>
#include <hip/hip_bf16.h>

// SegmentConv2d: fake-quant-int8 (global for x, per-128-oc-chunk for w) + 3x3 pad1 conv + bias.
// int8 path: quantize to real int8, conv with mfma_i32_16x16x64_i8 (exact int accum),
// scale+bias epilogue.
//
// Shapes: x[8][256][128][128] f32, w[512][256][3][3] f32, bias[512], out[8][512][128][128] f32.
//
// ws layout:
//   [0..255]        : amax[5] (uint bits, atomicMax) + 16B zero area at +64 (OOB redirect)
//   [256 ..)        : qx int8 NHWC  [n][h][w][c]  = 33,554,432 B
//   [256+32M ..)    : qw int8       [r*3+s][oc][c] = 1,179,648 B

typedef int i32x4 __attribute__((ext_vector_type(4)));

__device__ __forceinline__ void llds16(const void* g, void* l) {
    __builtin_amdgcn_global_load_lds(
        (const __attribute__((address_space(1))) void*)g,
        (__attribute__((address_space(3))) void*)l,
        16, 0, 0);
}

// ---------------- amax kernels ----------------
__global__ void k_amax_x(const float4* __restrict__ x, unsigned* __restrict__ dst) {
    int tid = blockIdx.x * 256 + threadIdx.x;        // 524288 threads
    float m = 0.f;
#pragma unroll 4
    for (int k = 0; k < 16; ++k) {                    // 8,388,608 float4 total
        float4 v = x[(size_t)tid + (size_t)k * 524288];
        m = fmaxf(m, fmaxf(fmaxf(fabsf(v.x), fabsf(v.y)), fmaxf(fabsf(v.z), fabsf(v.w))));
    }
    for (int off = 32; off > 0; off >>= 1) m = fmaxf(m, __shfl_xor(m, off, 64));
    if ((threadIdx.x & 63) == 0) atomicMax(dst, __float_as_uint(m));
}

__global__ void k_amax_w(const float4* __restrict__ w4, unsigned* __restrict__ dst) {
    int tid = blockIdx.x * 256 + threadIdx.x;        // 0..73727 (288 blocks)
    int chunk = blockIdx.y;                           // 0..3
    float4 v = w4[(size_t)chunk * 73728 + tid];
    float m = fmaxf(fmaxf(fabsf(v.x), fabsf(v.y)), fmaxf(fabsf(v.z), fabsf(v.w)));
    for (int off = 32; off > 0; off >>= 1) m = fmaxf(m, __shfl_xor(m, off, 64));
    if ((threadIdx.x & 63) == 0) atomicMax(dst + 1 + chunk, __float_as_uint(m));
}

// ---------------- quantize x : NCHW f32 -> NHWC int8 ----------------
// block = one (n,h) row, 256 threads. LDS transpose, padded uint[128][17] (conflict-free).
// NOTE: multiply by inv_scale (one divide per thread) -- fdiv per element was the
// round-1 prepass bottleneck.
__global__ void k_quant_x(const float* __restrict__ x, signed char* __restrict__ qx,
                          const unsigned* __restrict__ amaxb) {
    __shared__ unsigned tile[128 * 17];
    float inv = 127.0f / fmaxf(__uint_as_float(amaxb[0]), 1e-12f);
    int row = blockIdx.x;                 // n*128 + h
    int n = row >> 7, h = row & 127;
    int t = threadIdx.x;
    int w = t & 127, chalf = t >> 7;      // within wave, w = w0 + lane (coalesced)
    for (int cc = 0; cc < 4; ++cc) {
#pragma unroll
        for (int i = 0; i < 8; ++i) {
            int c0 = cc * 64 + chalf * 32 + i * 4;
            unsigned packed = 0;
#pragma unroll
            for (int j = 0; j < 4; ++j) {
                float v = x[((size_t)(n * 256 + c0 + j) * 128 + h) * 128 + w];
                float qf = fminf(fmaxf(rintf(v * inv), -128.f), 127.f);
                int qi = (int)qf;
                packed |= ((unsigned)(qi & 255)) << (8 * j);
            }
            tile[w * 17 + chalf * 8 + i] = packed;
        }
        __syncthreads();
#pragma unroll
        for (int i = 0; i < 2; ++i) {
            int idx = t + i * 256;         // 0..511
            int w2 = idx >> 2, q4 = idx & 3;
            unsigned u0 = tile[w2 * 17 + q4 * 4 + 0];
            unsigned u1 = tile[w2 * 17 + q4 * 4 + 1];
            unsigned u2 = tile[w2 * 17 + q4 * 4 + 2];
            unsigned u3 = tile[w2 * 17 + q4 * 4 + 3];
            uint4 val = make_uint4(u0, u1, u2, u3);
            *(uint4*)&qx[((size_t)row * 128 + w2) * 256 + cc * 64 + q4 * 16] = val;
        }
        __syncthreads();
    }
}

// ---------------- quantize w : OIHW f32 -> [rs][oc][c] int8 ----------------
__global__ void k_quant_w(const float* __restrict__ wsrc, signed char* __restrict__ qw,
                          const unsigned* __restrict__ amaxb) {
    int idx = blockIdx.x * 256 + threadIdx.x;   // 131072 = 512 blocks
    int oc = idx >> 8, c = idx & 255;
    float inv = 127.0f / fmaxf(__uint_as_float(amaxb[1 + (oc >> 7)]), 1e-12f);
    const float* src = wsrc + (size_t)idx * 9;
#pragma unroll
    for (int rs = 0; rs < 9; ++rs) {
        float qf = fminf(fmaxf(rintf(src[rs] * inv), -128.f), 127.f);
        qw[((size_t)(rs * 512 + oc)) * 256 + c] = (signed char)(int)qf;
    }
}

// ---------------- conv : implicit GEMM with mfma_i32_16x16x64_i8 ----------------
// grid 4096 (XCD-swizzled), block 256 (4 waves). Block tile: 64 oc x 256 px (2 rows).
// wave (rowsel = wid>>1, whalf = wid&1) owns 64oc x 64px.
// K-loop: r(3) x cb(4 blocks of 64 c); per step stage xs[2][130][64] + wt[3][64][64],
// then s(3) x 16 MFMA per wave.
// XCD swizzle: each XCD owns one image n -> qx working set ~1 MB stays in its L2.
// out written nontemporal so the 256MB stream doesn't evict qx.
__global__ __launch_bounds__(256) void k_conv(
    const signed char* __restrict__ qx, const signed char* __restrict__ qw,
    const signed char* __restrict__ zb, const unsigned* __restrict__ amaxb,
    const float* __restrict__ bias, float* __restrict__ out) {
    __shared__ __align__(16) signed char xs[2 * 130 * 64];   // [rowsel][w+1][c] 16640 B
    __shared__ __align__(16) signed char wt[3 * 64 * 64];    // [s][oc][c]      12288 B
    int orig = blockIdx.x;                      // 0..4095, nwg % 8 == 0
    int wgid = (orig & 7) * 512 + (orig >> 3);  // bijective XCD swizzle
    int rowpair = wgid >> 3, ocg = wgid & 7;
    int n = rowpair >> 6;                       // 64 rowpairs per image
    int h0 = (rowpair & 63) * 2;
    int t = threadIdx.x, wid = t >> 6, lane = t & 63;
    int p = lane & 15, hi = lane >> 4;
    int rowsel = wid >> 1, whalf = wid & 1;

    i32x4 acc[4][4] = {};

    for (int r = 0; r < 3; ++r) {
        int hhA = h0 - 1 + r;                   // input row for output row h0
        int hhB = h0 + r;                       // input row for output row h0+1
        bool okA = (hhA >= 0) && (hhA < 128);
        bool okB = (hhB < 128);
        const signed char* baseA = qx + (size_t)(n * 128 + (okA ? hhA : 0)) * 32768;
        const signed char* baseB = qx + (size_t)(n * 128 + (okB ? hhB : 0)) * 32768;
        for (int cb = 0; cb < 4; ++cb) {
            // stage xs: 1040 x 16B (2 rows x 130 w x 4 chunks), lane-linear LDS dest
#pragma unroll
            for (int i = 0; i < 5; ++i) {
                int idx = t + i * 256;
                if (idx < 1040) {
                    int rsel = (idx >= 520) ? 1 : 0;
                    int j = idx - rsel * 520;
                    int wr = j >> 2, q4 = j & 3;
                    int wg = wr - 1;
                    bool ok = rsel ? okB : okA;
                    const signed char* rb = rsel ? baseB : baseA;
                    const signed char* src = (ok && wg >= 0 && wg < 128)
                        ? rb + (size_t)wg * 256 + cb * 64 + q4 * 16
                        : zb;
                    llds16(src, xs + (i * 256 + wid * 64) * 16);
                }
            }
            // stage wt: 768 x 16B
#pragma unroll
            for (int i = 0; i < 3; ++i) {
                int idx = t + i * 256;
                int s = idx >> 8, rem = idx & 255;
                int oc = rem >> 2, q4 = rem & 3;
                const signed char* src = qw
                    + ((size_t)((r * 3 + s) * 512 + ocg * 64 + oc)) * 256 + cb * 64 + q4 * 16;
                llds16(src, wt + (i * 256 + wid * 64) * 16);
            }
            __syncthreads();
#pragma unroll
            for (int s = 0; s < 3; ++s) {
                i32x4 a[4], b[4];
#pragma unroll
                for (int mf = 0; mf < 4; ++mf)
                    a[mf] = *(const i32x4*)&wt[s * 4096 + (mf * 16 + p) * 64 + hi * 16];
#pragma unroll
                for (int nf = 0; nf < 4; ++nf)
                    b[nf] = *(const i32x4*)&xs[rowsel * 8320
                        + (whalf * 64 + nf * 16 + p + s) * 64 + hi * 16];
#pragma unroll
                for (int mf = 0; mf < 4; ++mf)
#pragma unroll
                    for (int nf = 0; nf < 4; ++nf)
                        acc[mf][nf] = __builtin_amdgcn_mfma_i32_16x16x64_i8(
                            a[mf], b[nf], acc[mf][nf], 0, 0, 0);
            }
            __syncthreads();
        }
    }

    float sx = fmaxf(__uint_as_float(amaxb[0]), 1e-12f) / 127.0f;
    float sw = fmaxf(__uint_as_float(amaxb[1 + (ocg >> 1)]), 1e-12f) / 127.0f;
    float sc = sx * sw;
    int h = h0 + rowsel;
#pragma unroll
    for (int mf = 0; mf < 4; ++mf)
#pragma unroll
        for (int nf = 0; nf < 4; ++nf)
#pragma unroll
            for (int j = 0; j < 4; ++j) {
                int oc = ocg * 64 + mf * 16 + hi * 4 + j;
                int px = whalf * 64 + nf * 16 + p;
                __builtin_nontemporal_store(
                    (float)acc[mf][nf][j] * sc + bias[oc],
                    &out[((size_t)(n * 512 + oc) * 128 + h) * 128 + px]);
            }
}

extern "C" void kernel_launch(void* const* d_in, const int* in_sizes, int n_in,
                              void* d_out, int out_size, void* d_ws, size_t ws_size,
                              hipStream_t stream) {
    const float* x    = (const float*)d_in[0];
    const float* wgt  = (const float*)d_in[1];
    const float* bias = (const float*)d_in[2];
    float* out = (float*)d_out;

    unsigned* amaxb = (unsigned*)d_ws;
    signed char* qx = (signed char*)d_ws + 256;
    signed char* qw = (signed char*)d_ws + 256 + 33554432;
    const signed char* zb = (const signed char*)d_ws + 64;   // 16B zeros for OOB redirect

    hipMemsetAsync(d_ws, 0, 256, stream);   // amax slots + zero area (graph-capturable)

    k_amax_x<<<2048, 256, 0, stream>>>((const float4*)x, amaxb);
    k_amax_w<<<dim3(288, 4), 256, 0, stream>>>((const float4*)wgt, amaxb);
    k_quant_x<<<1024, 256, 0, stream>>>(x, qx, amaxb);
    k_quant_w<<<512, 256, 0, stream>>>(wgt, qw, amaxb);
    k_conv<<<dim3(4096), 256, 0, stream>>>(qx, qw, zb, amaxb, bias, out);
}

// Round 3
// 350.840 us; speedup vs baseline: 1.1883x; 1.0415x over previous
//
#include <hip/hip_runtime.h>
#include <hip/hip_bf16.h>

// SegmentConv2d: fake-quant-int8 (global for x, per-128-oc-chunk for w) + 3x3 pad1 conv + bias.
// int8 path: quantize to real int8, conv with mfma_i32_16x16x64_i8 (exact int accum),
// scale+bias epilogue.
//
// Shapes: x[8][256][128][128] f32, w[512][256][3][3] f32, bias[512], out[8][512][128][128] f32.
//
// ws layout:
//   [0..255]        : amax[5] (uint bits, atomicMax) + 16B zero area at +64 (OOB redirect)
//   [256 ..)        : qx int8 NHWC  [n][h][w][c]  = 33,554,432 B
//   [256+32M ..)    : qw int8       [r*3+s][oc][c] = 1,179,648 B

typedef int i32x4 __attribute__((ext_vector_type(4)));

__device__ __forceinline__ void llds16(const void* g, void* l) {
    __builtin_amdgcn_global_load_lds(
        (const __attribute__((address_space(1))) void*)g,
        (__attribute__((address_space(3))) void*)l,
        16, 0, 0);
}

// ---------------- amax kernels ----------------
__global__ void k_amax_x(const float4* __restrict__ x, unsigned* __restrict__ dst) {
    int tid = blockIdx.x * 256 + threadIdx.x;        // 524288 threads
    float m = 0.f;
#pragma unroll 4
    for (int k = 0; k < 16; ++k) {                    // 8,388,608 float4 total
        float4 v = x[(size_t)tid + (size_t)k * 524288];
        m = fmaxf(m, fmaxf(fmaxf(fabsf(v.x), fabsf(v.y)), fmaxf(fabsf(v.z), fabsf(v.w))));
    }
    for (int off = 32; off > 0; off >>= 1) m = fmaxf(m, __shfl_xor(m, off, 64));
    if ((threadIdx.x & 63) == 0) atomicMax(dst, __float_as_uint(m));
}

__global__ void k_amax_w(const float4* __restrict__ w4, unsigned* __restrict__ dst) {
    int tid = blockIdx.x * 256 + threadIdx.x;        // 0..73727 (288 blocks)
    int chunk = blockIdx.y;                           // 0..3
    float4 v = w4[(size_t)chunk * 73728 + tid];
    float m = fmaxf(fmaxf(fabsf(v.x), fabsf(v.y)), fmaxf(fabsf(v.z), fabsf(v.w)));
    for (int off = 32; off > 0; off >>= 1) m = fmaxf(m, __shfl_xor(m, off, 64));
    if ((threadIdx.x & 63) == 0) atomicMax(dst + 1 + chunk, __float_as_uint(m));
}

// ---------------- quantize x : NCHW f32 -> NHWC int8 ----------------
// block = one (n,h) row, 256 threads. float4 vector reads (coalesced along w),
// pack 4 c-bytes per uint, XOR-swizzled word LDS transpose (2-way both sides),
// uint4 stores. Round-2 version was scalar-read latency-bound.
__global__ __launch_bounds__(256) void k_quant_x(const float* __restrict__ x,
                                                 signed char* __restrict__ qx,
                                                 const unsigned* __restrict__ amaxb) {
    __shared__ unsigned tile[128 * 68];   // [w][cword], row pitch 68 (16B-aligned rows)
    float inv = 127.0f / fmaxf(__uint_as_float(amaxb[0]), 1e-12f);
    int row = blockIdx.x;                 // n*128 + h
    int n = row >> 7, h = row & 127;
    int t = threadIdx.x;
    int w4 = t & 31, cg = t >> 5;         // w4: float4 slot along w; cg in [0,8)
    const float* base = x + (size_t)n * 256 * 16384 + (size_t)h * 128;
#pragma unroll
    for (int pp = 0; pp < 8; ++pp) {
        int c0 = pp * 32 + cg * 4;
        float4 v[4];
#pragma unroll
        for (int j = 0; j < 4; ++j)
            v[j] = *(const float4*)(base + (size_t)(c0 + j) * 16384 + w4 * 4);
#pragma unroll
        for (int i = 0; i < 4; ++i) {
            unsigned u = 0;
#pragma unroll
            for (int j = 0; j < 4; ++j) {
                float f = (&v[j].x)[i];
                int q = (int)fminf(fmaxf(rintf(f * inv), -128.f), 127.f);
                u |= ((unsigned)(q & 255)) << (8 * j);
            }
            int w = w4 * 4 + i;
            int cw = pp * 8 + cg;
            tile[(unsigned)(w * 68 + cw) ^ (((w >> 3) & 7) << 2)] = u;
        }
    }
    __syncthreads();
#pragma unroll
    for (int k = 0; k < 8; ++k) {
        int idx = t + k * 256;            // 0..2047
        int cq = idx & 15, w = idx >> 4;
        unsigned b = (unsigned)(w * 68 + cq * 4) ^ (((w >> 3) & 7) << 2);
        uint4 val = *(const uint4*)&tile[b];
        *(uint4*)&qx[(size_t)row * 32768 + (size_t)idx * 16] = val;
    }
}

// ---------------- quantize w : OIHW f32 -> [rs][oc][c] int8 ----------------
__global__ void k_quant_w(const float* __restrict__ wsrc, signed char* __restrict__ qw,
                          const unsigned* __restrict__ amaxb) {
    int idx = blockIdx.x * 256 + threadIdx.x;   // 131072 = 512 blocks
    int oc = idx >> 8, c = idx & 255;
    float inv = 127.0f / fmaxf(__uint_as_float(amaxb[1 + (oc >> 7)]), 1e-12f);
    const float* src = wsrc + (size_t)idx * 9;
#pragma unroll
    for (int rs = 0; rs < 9; ++rs) {
        float qf = fminf(fmaxf(rintf(src[rs] * inv), -128.f), 127.f);
        qw[((size_t)(rs * 512 + oc)) * 256 + c] = (signed char)(int)qf;
    }
}

// ---------------- conv : implicit GEMM with mfma_i32_16x16x64_i8 ----------------
// grid 4096 (bijective XCD swizzle: each XCD owns one image n), block 256 (4 waves).
// Block tile: 64 oc x 256 px (2 output rows). Wave (rowsel=wid>>1, whalf=wid&1) owns
// 64oc x 64px. Per c-block (cb of 64 c): stage ALL 4 input rows (h0-1..h0+2) and ALL
// 9 (r,s) weight planes -> ONE barrier pair per cb (4 total vs 12 in round 2), 144
// MFMA/wave between barriers. Fragment LDS reads XOR-swizzled (8-way -> 2-way);
// since global_load_lds writes linearly, the swizzle is applied by permuting the
// GLOBAL source q4 (both-sides rule).
__global__ __launch_bounds__(256) void k_conv(
    const signed char* __restrict__ qx, const signed char* __restrict__ qw,
    const signed char* __restrict__ zb, const unsigned* __restrict__ amaxb,
    const float* __restrict__ bias, float* __restrict__ out) {
    __shared__ __align__(16) signed char xs[4 * 8320];    // [rowk][wr 130][c 64] 33280 B
    __shared__ __align__(16) signed char wt[9 * 4096];    // [rs][oc 64][c 64]   36864 B
    int orig = blockIdx.x;                      // 0..4095, nwg % 8 == 0
    int wgid = (orig & 7) * 512 + (orig >> 3);  // bijective XCD swizzle
    int rowpair = wgid >> 3, ocg = wgid & 7;
    int n = rowpair >> 6;                       // 64 rowpairs per image
    int h0 = (rowpair & 63) * 2;
    int t = threadIdx.x, wid = t >> 6, lane = t & 63;
    int p = lane & 15, hi = lane >> 4;
    int rowsel = wid >> 1, whalf = wid & 1;

    i32x4 acc[4][4] = {};

    for (int cb = 0; cb < 4; ++cb) {
        // stage xs: 4 rows x 130 w x 4 q4 = 2080 x 16B, lane-linear LDS dest
#pragma unroll
        for (int i = 0; i < 9; ++i) {
            int idx = t + i * 256;
            if (idx < 2080) {
                int rowk = idx / 520;
                int j = idx - rowk * 520;
                int wr = j >> 2, q4 = j & 3;
                int wg = wr - 1;
                int hh = h0 - 1 + rowk;
                int q4s = q4 ^ ((wr >> 1) & 3);
                const signed char* src = (hh >= 0 && hh < 128 && wg >= 0 && wg < 128)
                    ? qx + (size_t)(n * 128 + hh) * 32768 + wg * 256 + cb * 64 + q4s * 16
                    : zb;
                llds16(src, xs + (size_t)(i * 256 + wid * 64) * 16);
            }
        }
        // stage wt: 9 rs x 64 oc x 4 q4 = 2304 x 16B
#pragma unroll
        for (int i = 0; i < 9; ++i) {
            int idx = t + i * 256;
            int rs = idx >> 8, rem = idx & 255;
            int oc = rem >> 2, q4 = rem & 3;
            int q4s = q4 ^ ((oc >> 1) & 3);
            const signed char* src = qw
                + (size_t)(rs * 512 + ocg * 64 + oc) * 256 + cb * 64 + q4s * 16;
            llds16(src, wt + (size_t)(i * 256 + wid * 64) * 16);
        }
        __syncthreads();
#pragma unroll
        for (int r = 0; r < 3; ++r) {
            int rowk = r + rowsel;
#pragma unroll
            for (int s = 0; s < 3; ++s) {
                i32x4 a[4], b[4];
#pragma unroll
                for (int mf = 0; mf < 4; ++mf) {
                    int ocr = mf * 16 + p;
                    a[mf] = *(const i32x4*)&wt[(r * 3 + s) * 4096 + ocr * 64
                                               + ((hi ^ ((ocr >> 1) & 3)) << 4)];
                }
#pragma unroll
                for (int nf = 0; nf < 4; ++nf) {
                    int wrow = whalf * 64 + nf * 16 + p + s;
                    b[nf] = *(const i32x4*)&xs[rowk * 8320 + wrow * 64
                                               + ((hi ^ ((wrow >> 1) & 3)) << 4)];
                }
#pragma unroll
                for (int mf = 0; mf < 4; ++mf)
#pragma unroll
                    for (int nf = 0; nf < 4; ++nf)
                        acc[mf][nf] = __builtin_amdgcn_mfma_i32_16x16x64_i8(
                            a[mf], b[nf], acc[mf][nf], 0, 0, 0);
            }
        }
        __syncthreads();
    }

    float sx = fmaxf(__uint_as_float(amaxb[0]), 1e-12f) / 127.0f;
    float sw = fmaxf(__uint_as_float(amaxb[1 + (ocg >> 1)]), 1e-12f) / 127.0f;
    float sc = sx * sw;
    int h = h0 + rowsel;
#pragma unroll
    for (int mf = 0; mf < 4; ++mf)
#pragma unroll
        for (int nf = 0; nf < 4; ++nf)
#pragma unroll
            for (int j = 0; j < 4; ++j) {
                int oc = ocg * 64 + mf * 16 + hi * 4 + j;
                int px = whalf * 64 + nf * 16 + p;
                out[((size_t)(n * 512 + oc) * 128 + h) * 128 + px] =
                    (float)acc[mf][nf][j] * sc + bias[oc];
            }
}

extern "C" void kernel_launch(void* const* d_in, const int* in_sizes, int n_in,
                              void* d_out, int out_size, void* d_ws, size_t ws_size,
                              hipStream_t stream) {
    const float* x    = (const float*)d_in[0];
    const float* wgt  = (const float*)d_in[1];
    const float* bias = (const float*)d_in[2];
    float* out = (float*)d_out;

    unsigned* amaxb = (unsigned*)d_ws;
    signed char* qx = (signed char*)d_ws + 256;
    signed char* qw = (signed char*)d_ws + 256 + 33554432;
    const signed char* zb = (const signed char*)d_ws + 64;   // 16B zeros for OOB redirect

    hipMemsetAsync(d_ws, 0, 256, stream);   // amax slots + zero area (graph-capturable)

    k_amax_x<<<2048, 256, 0, stream>>>((const float4*)x, amaxb);
    k_amax_w<<<dim3(288, 4), 256, 0, stream>>>((const float4*)wgt, amaxb);
    k_quant_x<<<1024, 256, 0, stream>>>(x, qx, amaxb);
    k_quant_w<<<512, 256, 0, stream>>>(wgt, qw, amaxb);
    k_conv<<<dim3(4096), 256, 0, stream>>>(qx, qw, zb, amaxb, bias, out);
}